// Round 2
// baseline (569.758 us; speedup 1.0000x reference)
//
#include <hip/hip_runtime.h>

typedef _Float16 f16;
typedef _Float16 f16x8 __attribute__((ext_vector_type(8)));
typedef _Float16 f16x4 __attribute__((ext_vector_type(4)));
typedef float    f32x4 __attribute__((ext_vector_type(4)));

constexpr int kBS  = 8;
constexpr int kT   = 256;
constexpr int kNJ  = 24;
constexpr int kDIM = 512;
constexpr int kNH  = 8;
constexpr int kHD  = 64;
constexpr int kRS  = kNJ * kDIM;          // 12288, row stride of (b,t) rows
constexpr int kBT  = kBS * kT;            // 2048
constexpr int kROWS = kBT * kNJ;          // 49152

// ---- async global->LDS, 16B per lane; LDS dest is wave-uniform base + lane*16 ----
__device__ __forceinline__ void gload_lds16(const void* g, void* l) {
  auto gp = (const __attribute__((address_space(1))) unsigned int*)g;
  auto lp = (__attribute__((address_space(3))) unsigned int*)l;
  __builtin_amdgcn_global_load_lds(gp, lp, 16, 0, 0);
}

// ================= elementwise f32 -> f16 =================
__global__ __launch_bounds__(256) void k_cvt(const float* __restrict__ in,
                                             f16* __restrict__ out, int n4) {
  int i = blockIdx.x * blockDim.x + threadIdx.x;
  int stride = gridDim.x * blockDim.x;
  for (; i < n4; i += stride) {
    float4 v = ((const float4*)in)[i];
    f16x4 h;
    h[0] = (f16)v.x; h[1] = (f16)v.y; h[2] = (f16)v.z; h[3] = (f16)v.w;
    ((f16x4*)out)[i] = h;
  }
}

// ============ transpose-convert W[j][d][e] f32 -> WT[j][e][d] f16 ============
__global__ __launch_bounds__(256) void k_cvt_wT(const float* __restrict__ W,
                                                f16* __restrict__ WT) {
  int bx = blockIdx.x;            // 256 tiles of 32x32
  int et = bx & 15, dt = bx >> 4;
  int j  = blockIdx.y;
  __shared__ float tile[32][33];
  int tid = threadIdx.x;
  int r = tid >> 3, c4 = (tid & 7) * 4;
  const float* src = W + ((size_t)j * 512 + (dt * 32 + r)) * 512 + et * 32 + c4;
  float4 v = *(const float4*)src;
  tile[r][c4 + 0] = v.x; tile[r][c4 + 1] = v.y;
  tile[r][c4 + 2] = v.z; tile[r][c4 + 3] = v.w;
  __syncthreads();
  f16x4 h;
  h[0] = (f16)tile[c4 + 0][r]; h[1] = (f16)tile[c4 + 1][r];
  h[2] = (f16)tile[c4 + 2][r]; h[3] = (f16)tile[c4 + 3][r];
  f16* dst = WT + ((size_t)j * 512 + (et * 32 + r)) * 512 + dt * 32 + c4;
  *(f16x4*)dst = h;
}

// ============ 128x128 tile GEMM, C = A * B^T ; K = 512, BK = 64 ============
// A: [128 rows][K] row stride lda ; Bt: [128 rows][K] row stride 512
// LDS chunk-swizzle: slot chunk = global chunk ^ (row & 7)   (chunk = 16B)
template <bool OUT_F32>
__device__ __forceinline__ void gemm_tile_128(const f16* __restrict__ A, int lda,
                                              const f16* __restrict__ Bt,
                                              void* __restrict__ Cp, int ldc,
                                              const float* __restrict__ bias) {
  __shared__ f16 As[128 * 64];
  __shared__ f16 Bs[128 * 64];
  int tid = threadIdx.x, lane = tid & 63, wave = tid >> 6;
  int wm = wave >> 1, wn = wave & 1;
  int lr = lane >> 3, cs = lane & 7;
  int fr = lane & 15, fq = lane >> 4;
  f32x4 acc[4][4] = {};

  for (int k0 = 0; k0 < 512; k0 += 64) {
    for (int i = 0; i < 4; ++i) {
      int row = wave * 32 + i * 8 + lr;
      int csrc = cs ^ (row & 7);
      gload_lds16(A + (size_t)row * lda + k0 + csrc * 8, As + (wave * 32 + i * 8) * 64);
      gload_lds16(Bt + (size_t)row * 512 + k0 + csrc * 8, Bs + (wave * 32 + i * 8) * 64);
    }
    __syncthreads();
    for (int kc = 0; kc < 2; ++kc) {
      f16x8 af[4], bf[4];
      for (int m = 0; m < 4; ++m) {
        int row = wm * 64 + m * 16 + fr;
        int chunk = kc * 4 + fq;
        af[m] = *(const f16x8*)((const char*)As + row * 128 + ((chunk ^ (row & 7)) << 4));
      }
      for (int n = 0; n < 4; ++n) {
        int row = wn * 64 + n * 16 + fr;
        int chunk = kc * 4 + fq;
        bf[n] = *(const f16x8*)((const char*)Bs + row * 128 + ((chunk ^ (row & 7)) << 4));
      }
      for (int m = 0; m < 4; ++m)
        for (int n = 0; n < 4; ++n)
          acc[m][n] = __builtin_amdgcn_mfma_f32_16x16x32_f16(af[m], bf[n], acc[m][n], 0, 0, 0);
    }
    __syncthreads();
  }
  // epilogue: C/D layout row=(lane>>4)*4+reg, col=lane&15 (m89-verified)
  for (int m = 0; m < 4; ++m)
    for (int n = 0; n < 4; ++n)
      for (int r = 0; r < 4; ++r) {
        int row = wm * 64 + m * 16 + fq * 4 + r;
        int col = wn * 64 + n * 16 + fr;
        if constexpr (OUT_F32) {
          ((float*)Cp)[(size_t)row * ldc + col] = acc[m][n][r] + bias[col];
        } else {
          ((f16*)Cp)[(size_t)row * ldc + col] = (f16)acc[m][n][r];
        }
      }
}

// ============ QKV projection: per (j, sel) GEMM [2048,512]@[512,512]^T ============
__global__ __launch_bounds__(256) void k_qkv(const f16* __restrict__ xh,
                                             const f16* __restrict__ wT,
                                             f16* __restrict__ q, f16* __restrict__ k,
                                             f16* __restrict__ v) {
  int bid = blockIdx.x;           // 64 = 16 mtiles * 4 ntiles
  int nt = bid & 3, mt = bid >> 2;
  int j = blockIdx.y, sel = blockIdx.z;
  const f16* A = xh + (size_t)j * kDIM + (size_t)mt * 128 * kRS;
  const f16* Bt = wT + ((size_t)sel * kNJ + j) * 262144 + (size_t)nt * 128 * 512;
  f16* outp = (sel == 0) ? q : (sel == 1) ? k : v;
  f16* C = outp + (size_t)j * kDIM + (size_t)mt * 128 * kRS + nt * 128;
  gemm_tile_128<false>(A, kRS, Bt, C, kRS, nullptr);
}

// ============ output projection: [49152,512]@Wo^T + bo -> f32 ============
__global__ __launch_bounds__(256) void k_outproj(const f16* __restrict__ O,
                                                 const f16* __restrict__ woh,
                                                 const float* __restrict__ bo,
                                                 float* __restrict__ y) {
  int bid = blockIdx.x;           // 384 mtiles * 4 ntiles
  int nt = bid & 3, mt = bid >> 2;
  const f16* A = O + (size_t)mt * 128 * 512;
  const f16* Bt = woh + (size_t)nt * 128 * 512;
  float* C = y + (size_t)mt * 128 * 512 + nt * 128;
  gemm_tile_128<true>(A, 512, Bt, C, 512, bo + nt * 128);
}

// ============ attention: one block per (b, j, h); 4 waves; 16-row Q tiles ============
__global__ __launch_bounds__(256) void k_attn(const f16* __restrict__ q,
                                              const f16* __restrict__ k,
                                              const f16* __restrict__ v,
                                              f16* __restrict__ o) {
  int bid = blockIdx.x;
  int h = bid & 7, j = (bid >> 3) % kNJ, b = bid / (kNH * kNJ);
  __shared__ f16 Ks[256 * 64];     // [s][d], rows 128B, chunk-swizzled
  __shared__ f16 Vt[64 * 256];     // [d][s], rows 512B, chunk-swizzled
  __shared__ f16 Ps[4 * 16 * 256]; // per-wave P tile [16][256], chunk-swizzled
  int tid = threadIdx.x, lane = tid & 63, wave = tid >> 6;
  int fr = lane & 15, fq = lane >> 4;
  size_t base = ((size_t)b * kT * kNJ + j) * kDIM + h * kHD;  // + t*kRS + d

  // stage K (global_load_lds, pre-swizzled source chunks)
  for (int i = 0; i < 8; ++i) {
    int row = wave * 64 + i * 8 + (lane >> 3);
    int csrc = (lane & 7) ^ (row & 7);
    gload_lds16(k + base + (size_t)row * kRS + csrc * 8, Ks + (wave * 64 + i * 8) * 64);
  }
  // stage V transposed (reg round-trip, scatter ds_write_b16)
  for (int i = 0; i < 8; ++i) {
    int s = i * 32 + (tid >> 3);
    int d0 = (tid & 7) * 8;
    f16x8 vv = *(const f16x8*)(v + base + (size_t)s * kRS + d0);
    for (int u = 0; u < 8; ++u) {
      int d = d0 + u;
      int chunk = s >> 3;
      int byteoff = d * 512 + (((chunk ^ (d & 7))) << 4) + (s & 7) * 2;
      *(f16*)((char*)Vt + byteoff) = vv[u];
    }
  }
  __syncthreads();

  f16* P = Ps + wave * 16 * 256;
  for (int qt = 0; qt < 4; ++qt) {
    int trow = wave * 64 + qt * 16 + fr;
    const f16* qrow = q + base + (size_t)trow * kRS + fq * 8;
    f16x8 qa0 = *(const f16x8*)(qrow);
    f16x8 qa1 = *(const f16x8*)(qrow + 32);

    // S = Q K^T  (A=Q rows t, B^T=K rows s)
    f32x4 s_acc[16] = {};
    for (int ct = 0; ct < 16; ++ct) {
      {
        int row = ct * 16 + fr, chunk = fq;
        f16x8 bf = *(const f16x8*)((const char*)Ks + row * 128 + ((chunk ^ (row & 7)) << 4));
        s_acc[ct] = __builtin_amdgcn_mfma_f32_16x16x32_f16(qa0, bf, s_acc[ct], 0, 0, 0);
      }
      {
        int row = ct * 16 + fr, chunk = 4 + fq;
        f16x8 bf = *(const f16x8*)((const char*)Ks + row * 128 + ((chunk ^ (row & 7)) << 4));
        s_acc[ct] = __builtin_amdgcn_mfma_f32_16x16x32_f16(qa1, bf, s_acc[ct], 0, 0, 0);
      }
    }

    // wave-parallel softmax over s: rows owned by (fq, reg); cols spread over 16 lanes
    const float scale = 0.125f;  // hd^-0.5
    float linv[4];
    for (int r = 0; r < 4; ++r) {
      float m = -1e30f;
      for (int ct = 0; ct < 16; ++ct) m = fmaxf(m, s_acc[ct][r]);
      for (int dd = 1; dd < 16; dd <<= 1) m = fmaxf(m, __shfl_xor(m, dd));
      m *= scale;
      float lsum = 0.f;
      for (int ct = 0; ct < 16; ++ct) {
        float p = __expf(s_acc[ct][r] * scale - m);
        s_acc[ct][r] = p;
        lsum += p;
      }
      for (int dd = 1; dd < 16; dd <<= 1) lsum += __shfl_xor(lsum, dd);
      linv[r] = 1.0f / lsum;
    }

    // P -> f16 -> wave-private LDS [16][256] (chunk-swizzled)
    for (int ct = 0; ct < 16; ++ct)
      for (int r = 0; r < 4; ++r) {
        int row = fq * 4 + r;
        int col = ct * 16 + fr;
        int chunk = col >> 3;
        int byteoff = row * 512 + ((chunk ^ (row & 7)) << 4) + (col & 7) * 2;
        *(f16*)((char*)P + byteoff) = (f16)s_acc[ct][r];
      }

    // O = P V  (A=P rows t, B^T = V^T rows d); wave-private P, compiler
    // inserts the same-wave lgkmcnt wait — no __syncthreads needed.
    f16x8 pa[8];
    for (int kc = 0; kc < 8; ++kc) {
      int row = fr, chunk = kc * 4 + fq;
      pa[kc] = *(const f16x8*)((const char*)P + row * 512 + ((chunk ^ (row & 7)) << 4));
    }
    f32x4 oacc[4] = {};
    for (int nt = 0; nt < 4; ++nt)
      for (int kc = 0; kc < 8; ++kc) {
        int row = nt * 16 + fr, chunk = kc * 4 + fq;
        f16x8 bf = *(const f16x8*)((const char*)Vt + row * 512 + ((chunk ^ (row & 7)) << 4));
        oacc[nt] = __builtin_amdgcn_mfma_f32_16x16x32_f16(pa[kc], bf, oacc[nt], 0, 0, 0);
      }

    // epilogue: divide by row sum, store f16
    for (int r = 0; r < 4; ++r) {
      int trow2 = wave * 64 + qt * 16 + fq * 4 + r;
      for (int nt = 0; nt < 4; ++nt) {
        int d = nt * 16 + fr;
        o[base + (size_t)trow2 * kRS + d] = (f16)(oacc[nt][r] * linv[r]);
      }
    }
  }
}

// ================================ launch ================================
extern "C" void kernel_launch(void* const* d_in, const int* in_sizes, int n_in,
                              void* d_out, int out_size, void* d_ws, size_t ws_size,
                              hipStream_t stream) {
  const float* x  = (const float*)d_in[0];
  const float* Wq = (const float*)d_in[1];
  const float* Wk = (const float*)d_in[2];
  const float* Wv = (const float*)d_in[3];
  const float* Wo = (const float*)d_in[4];
  const float* bo = (const float*)d_in[5];
  float* y = (float*)d_out;

  char* ws = (char*)d_ws;
  // workspace layout (bytes)
  f16* xh  = (f16*)(ws);                 // 50,331,648  (also reused as attn out)
  f16* wT  = (f16*)(ws + 50331648);      // 37,748,736
  f16* woh = (f16*)(ws + 88080384);      //    524,288
  f16* q   = (f16*)(ws + 88604672);      // 50,331,648
  f16* k   = (f16*)(ws + 138936320);     // 50,331,648
  f16* v   = (f16*)(ws + 189267968);     // 50,331,648  (total ~228.5 MiB)
  f16* o   = xh;                         // alias: xh dead after k_qkv

  k_cvt<<<4096, 256, 0, stream>>>(x, xh, (kBS * kT * kNJ * kDIM) / 4);
  k_cvt<<<256, 256, 0, stream>>>(Wo, woh, (kDIM * kDIM) / 4);
  dim3 gT(256, kNJ);
  k_cvt_wT<<<gT, 256, 0, stream>>>(Wq, wT);
  k_cvt_wT<<<gT, 256, 0, stream>>>(Wk, wT + 6291456);
  k_cvt_wT<<<gT, 256, 0, stream>>>(Wv, wT + 12582912);

  k_qkv<<<dim3(64, kNJ, 3), 256, 0, stream>>>(xh, wT, q, k, v);
  k_attn<<<kBS * kNJ * kNH, 256, 0, stream>>>(q, k, v, o);
  k_outproj<<<1536, 256, 0, stream>>>(o, woh, bo, y);
}

// Round 5
// 564.508 us; speedup vs baseline: 1.0093x; 1.0093x over previous
//
#include <hip/hip_runtime.h>

typedef _Float16 f16;
typedef _Float16 f16x8 __attribute__((ext_vector_type(8)));
typedef _Float16 f16x4 __attribute__((ext_vector_type(4)));
typedef float    f32x4 __attribute__((ext_vector_type(4)));

constexpr int kBS  = 8;
constexpr int kT   = 256;
constexpr int kNJ  = 24;
constexpr int kDIM = 512;
constexpr int kNH  = 8;
constexpr int kHD  = 64;
constexpr int kRS  = kNJ * kDIM;          // 12288
constexpr int kBT  = kBS * kT;            // 2048
constexpr int kHEADSZ = kT * kHD;         // 16384 elements per (b,j,h) head block

// ---- async global->LDS, 16B per lane; LDS dest = wave-uniform base + lane*16 ----
__device__ __forceinline__ void gload_lds16(const void* g, void* l) {
  auto gp = (const __attribute__((address_space(1))) unsigned int*)g;
  auto lp = (__attribute__((address_space(3))) unsigned int*)l;
  __builtin_amdgcn_global_load_lds(gp, lp, 16, 0, 0);
}

// ================= x [R][j][d] f32 -> xh [j][R][d] f16 =================
__global__ __launch_bounds__(256) void k_cvt_xj(const float* __restrict__ in,
                                                f16* __restrict__ out, int n4) {
  int i = blockIdx.x * blockDim.x + threadIdx.x;
  int stride = gridDim.x * blockDim.x;
  for (; i < n4; i += stride) {
    float4 v = ((const float4*)in)[i];
    f16x4 h;
    h[0] = (f16)v.x; h[1] = (f16)v.y; h[2] = (f16)v.z; h[3] = (f16)v.w;
    int e0 = i * 4;
    int R = e0 / kRS;
    int rem = e0 - R * kRS;
    int j = rem >> 9;
    int d = rem & 511;
    ((f16x4*)out)[j * 262144 + R * 128 + (d >> 2)] = h;
  }
}

// ================= plain f32 -> f16 (same layout) =================
__global__ __launch_bounds__(256) void k_cvt(const float* __restrict__ in,
                                             f16* __restrict__ out, int n4) {
  int i = blockIdx.x * blockDim.x + threadIdx.x;
  int stride = gridDim.x * blockDim.x;
  for (; i < n4; i += stride) {
    float4 v = ((const float4*)in)[i];
    f16x4 h;
    h[0] = (f16)v.x; h[1] = (f16)v.y; h[2] = (f16)v.z; h[3] = (f16)v.w;
    ((f16x4*)out)[i] = h;
  }
}

// ============ transpose-convert W[j][d][e] f32 -> WT[j][e][d] f16 ============
__global__ __launch_bounds__(256) void k_cvt_wT(const float* __restrict__ W,
                                                f16* __restrict__ WT) {
  int bx = blockIdx.x;            // 256 tiles of 32x32
  int et = bx & 15, dt = bx >> 4;
  int j  = blockIdx.y;
  __shared__ float tile[32][33];
  int tid = threadIdx.x;
  int r = tid >> 3, c4 = (tid & 7) * 4;
  const float* src = W + ((size_t)j * 512 + (dt * 32 + r)) * 512 + et * 32 + c4;
  float4 v = *(const float4*)src;
  tile[r][c4 + 0] = v.x; tile[r][c4 + 1] = v.y;
  tile[r][c4 + 2] = v.z; tile[r][c4 + 3] = v.w;
  __syncthreads();
  f16x4 h;
  h[0] = (f16)tile[c4 + 0][r]; h[1] = (f16)tile[c4 + 1][r];
  h[2] = (f16)tile[c4 + 2][r]; h[3] = (f16)tile[c4 + 3][r];
  f16* dst = WT + ((size_t)j * 512 + (et * 32 + r)) * 512 + dt * 32 + c4;
  *(f16x4*)dst = h;
}

// ============ 128x128 tile acc compute, C = A * B^T ; K=512, lda=ldb=512 ============
// LDS chunk-swizzle: slot chunk = global chunk ^ (row & 7)   (chunk = 16B)
__device__ __forceinline__ void gemm_acc_128(const f16* __restrict__ A,
                                             const f16* __restrict__ Bt,
                                             f32x4 (&acc)[4][4],
                                             f16* As, f16* Bs) {
  int tid = threadIdx.x, lane = tid & 63, wave = tid >> 6;
  int wm = wave >> 1, wn = wave & 1;
  int lr = lane >> 3, cs = lane & 7;
  int fr = lane & 15, fq = lane >> 4;

  for (int k0 = 0; k0 < 512; k0 += 64) {
#pragma unroll
    for (int i = 0; i < 4; ++i) {
      int row = wave * 32 + i * 8 + lr;
      int csrc = cs ^ (row & 7);
      gload_lds16(A + (size_t)row * 512 + k0 + csrc * 8, As + (wave * 32 + i * 8) * 64);
      gload_lds16(Bt + (size_t)row * 512 + k0 + csrc * 8, Bs + (wave * 32 + i * 8) * 64);
    }
    __syncthreads();
#pragma unroll
    for (int kc = 0; kc < 2; ++kc) {
      f16x8 af[4], bf[4];
#pragma unroll
      for (int m = 0; m < 4; ++m) {
        int row = wm * 64 + m * 16 + fr;
        int chunk = kc * 4 + fq;
        af[m] = *(const f16x8*)((const char*)As + row * 128 + ((chunk ^ (row & 7)) << 4));
      }
#pragma unroll
      for (int n = 0; n < 4; ++n) {
        int row = wn * 64 + n * 16 + fr;
        int chunk = kc * 4 + fq;
        bf[n] = *(const f16x8*)((const char*)Bs + row * 128 + ((chunk ^ (row & 7)) << 4));
      }
#pragma unroll
      for (int m = 0; m < 4; ++m)
#pragma unroll
        for (int n = 0; n < 4; ++n)
          acc[m][n] = __builtin_amdgcn_mfma_f32_16x16x32_f16(af[m], bf[n], acc[m][n], 0, 0, 0);
    }
    __syncthreads();
  }
}

// ============ QKV projection: per (j, sel) GEMM [2048,512]@[512,512]^T ============
// q,k out: blocked [b][j][h][t][d]; v out: transposed [b][j][h][d][t]
__global__ __launch_bounds__(256) void k_qkv(const f16* __restrict__ xh,
                                             const f16* __restrict__ wT,
                                             f16* __restrict__ q, f16* __restrict__ k,
                                             f16* __restrict__ v) {
  __shared__ f16 As[128 * 64];
  __shared__ f16 Bs[128 * 64];
  int bid = blockIdx.x;                      // 64 = 16 mt * 4 nt, XCD-swizzled
  int s = (bid & 7) * 8 + (bid >> 3);        // bijective (64 % 8 == 0)
  int nt = s & 3, mt = s >> 2;
  int j = blockIdx.y, sel = blockIdx.z;
  const f16* A = xh + (size_t)j * 1048576 + (size_t)mt * 128 * 512;
  const f16* Bt = wT + ((size_t)sel * kNJ + j) * 262144 + (size_t)nt * 128 * 512;
  f32x4 acc[4][4] = {};
  gemm_acc_128(A, Bt, acc, As, Bs);

  int lane = threadIdx.x & 63, wave = threadIdx.x >> 6;
  int wm = wave >> 1, wn = wave & 1;
  int fr = lane & 15, fq = lane >> 4;
  if (sel < 2) {
    f16* dst = (sel == 0) ? q : k;
#pragma unroll
    for (int m = 0; m < 4; ++m)
#pragma unroll
      for (int n = 0; n < 4; ++n) {
        int colb = nt * 128 + wn * 64 + n * 16;
        int h = colb >> 6, d0 = colb & 63;
        int R0 = mt * 128 + wm * 64 + m * 16 + fq * 4;
        int b = R0 >> 8, t0 = R0 & 255;
        size_t hb = ((size_t)(b * kNJ + j) * kNH + h) * kHEADSZ;
#pragma unroll
        for (int r = 0; r < 4; ++r)
          dst[hb + (size_t)(t0 + r) * 64 + d0 + fr] = (f16)acc[m][n][r];
      }
  } else {
#pragma unroll
    for (int m = 0; m < 4; ++m)
#pragma unroll
      for (int n = 0; n < 4; ++n) {
        int colb = nt * 128 + wn * 64 + n * 16;
        int h = colb >> 6, d0 = colb & 63;
        int R0 = mt * 128 + wm * 64 + m * 16 + fq * 4;
        int b = R0 >> 8, t0 = R0 & 255;
        size_t hb = ((size_t)(b * kNJ + j) * kNH + h) * kHEADSZ;
        f16x4 ov;
#pragma unroll
        for (int r = 0; r < 4; ++r) ov[r] = (f16)acc[m][n][r];
        *(f16x4*)(v + hb + (size_t)(d0 + fr) * kT + t0) = ov;   // [d][t], 8B aligned
      }
  }
}

// ============ output projection: [49152,512]@Wo^T + bo -> f32 ============
__global__ __launch_bounds__(256) void k_outproj(const f16* __restrict__ O,
                                                 const f16* __restrict__ woh,
                                                 const float* __restrict__ bo,
                                                 float* __restrict__ y) {
  __shared__ f16 As[128 * 64];
  __shared__ f16 Bs[128 * 64];
  int bid = blockIdx.x;           // 384 mt * 4 nt
  int nt = bid & 3, mt = bid >> 2;
  const f16* A = O + (size_t)mt * 128 * 512;
  const f16* Bt = woh + (size_t)nt * 128 * 512;
  float* C = y + (size_t)mt * 128 * 512 + nt * 128;
  f32x4 acc[4][4] = {};
  gemm_acc_128(A, Bt, acc, As, Bs);

  int lane = threadIdx.x & 63, wave = threadIdx.x >> 6;
  int wm = wave >> 1, wn = wave & 1;
  int fr = lane & 15, fq = lane >> 4;
  const float* bias = bo + nt * 128;
#pragma unroll
  for (int m = 0; m < 4; ++m)
#pragma unroll
    for (int n = 0; n < 4; ++n)
#pragma unroll
      for (int r = 0; r < 4; ++r) {
        int row = wm * 64 + m * 16 + fq * 4 + r;
        int col = wn * 64 + n * 16 + fr;
        C[(size_t)row * 512 + col] = acc[m][n][r] + bias[col];
      }
}

// ============ attention: one block per (b,j,h); 4 waves x 64 t-rows ============
// Swapped QK^T: S^T = mfma(K, Q) -> lane(fq,fr): s = ct*16+fq*4+r, t = fr.
// This IS the 16x16x16 B-frag layout of P -> PV directly from registers.
__global__ __launch_bounds__(256, 2) void k_attn(const f16* __restrict__ q,
                                                 const f16* __restrict__ k,
                                                 const f16* __restrict__ v,
                                                 f16* __restrict__ o) {
  int bid = blockIdx.x;
  int h = bid & 7, j = (bid >> 3) % kNJ, b = bid / (kNH * kNJ);
  __shared__ f16 Ks[256 * 64];     // [s][d], rows 128B, chunk-swizzled
  __shared__ f16 Vt[64 * 256];     // [d][t], rows 512B, chunk-swizzled
  int tid = threadIdx.x, lane = tid & 63, wave = tid >> 6;
  int fr = lane & 15, fq = lane >> 4;
  size_t hb = ((size_t)(b * kNJ + j) * kNH + h) * kHEADSZ;
  const f16* qh = q + hb;
  const f16* kh = k + hb;
  const f16* vth = v + hb;

  // stage K: linear gload, pre-swizzled source (slot cs holds global chunk cs^(row&7))
#pragma unroll
  for (int i = 0; i < 8; ++i) {
    int row = wave * 64 + i * 8 + (lane >> 3);
    int g = (lane & 7) ^ (row & 7);
    gload_lds16(kh + row * 64 + g * 8, Ks + (wave * 64 + i * 8) * 64);
  }
  // stage V^T: linear gload from v_t[d][t]; swizzle via per-lane source chunk
#pragma unroll
  for (int p = 0; p < 8; ++p) {
    int off = wave * 8192 + p * 1024 + lane * 16;   // byte offset in Vt
    int d = off >> 9;
    int cs = (off >> 4) & 31;
    int g = cs ^ (d & 7);
    gload_lds16(vth + d * 256 + g * 8, (char*)Vt + wave * 8192 + p * 1024);
  }
  __syncthreads();

  const float scale = 0.125f;  // hd^-0.5
  for (int qt = 0; qt < 4; ++qt) {
    int trow = wave * 64 + qt * 16 + fr;
    const f16* qrow = qh + trow * 64 + fq * 8;
    f16x8 qa0 = *(const f16x8*)(qrow);
    f16x8 qa1 = *(const f16x8*)(qrow + 32);

    // S^T = K Q^T
    f32x4 s_acc[16] = {};
#pragma unroll
    for (int ct = 0; ct < 16; ++ct) {
      int row = ct * 16 + fr;
      f16x8 a0 = *(const f16x8*)((const char*)Ks + row * 128 + ((fq ^ (row & 7)) << 4));
      s_acc[ct] = __builtin_amdgcn_mfma_f32_16x16x32_f16(a0, qa0, s_acc[ct], 0, 0, 0);
      f16x8 a1 = *(const f16x8*)((const char*)Ks + row * 128 + (((4 + fq) ^ (row & 7)) << 4));
      s_acc[ct] = __builtin_amdgcn_mfma_f32_16x16x32_f16(a1, qa1, s_acc[ct], 0, 0, 0);
    }

    // softmax over s for column t=fr: lane-local 64 values + 2 shfl over fq
    float mx = -1e30f;
#pragma unroll
    for (int ct = 0; ct < 16; ++ct)
#pragma unroll
      for (int r = 0; r < 4; ++r) mx = fmaxf(mx, s_acc[ct][r]);
    mx = fmaxf(mx, __shfl_xor(mx, 16));
    mx = fmaxf(mx, __shfl_xor(mx, 32));
    mx *= scale;
    float lsum = 0.f;
#pragma unroll
    for (int ct = 0; ct < 16; ++ct)
#pragma unroll
      for (int r = 0; r < 4; ++r) {
        float p = __expf(s_acc[ct][r] * scale - mx);
        s_acc[ct][r] = p;
        lsum += p;
      }
    lsum += __shfl_xor(lsum, 16);
    lsum += __shfl_xor(lsum, 32);
    float linv = 1.0f / lsum;

    // P -> f16 in-register (already in 16x16x16 B-frag layout)
    f16x4 pb[16];
#pragma unroll
    for (int ct = 0; ct < 16; ++ct)
#pragma unroll
      for (int r = 0; r < 4; ++r) pb[ct][r] = (f16)s_acc[ct][r];

    // O^T = V^T P : A-frag = V^T rows d (from Vt), B-frag = pb
    f32x4 oacc[4] = {};
#pragma unroll
    for (int nt = 0; nt < 4; ++nt) {
      int d = nt * 16 + fr;
#pragma unroll
      for (int ks = 0; ks < 16; ++ks) {
        int byteoff = d * 512 + (((2 * ks + (fq >> 1)) ^ (d & 7)) << 4) + (fq & 1) * 8;
        f16x4 va = *(const f16x4*)((const char*)Vt + byteoff);
        oacc[nt] = __builtin_amdgcn_mfma_f32_16x16x16f16(va, pb[ks], oacc[nt], 0, 0, 0);
      }
    }

    // store: lane(fq,fr) holds d = nt*16+fq*4+r for t = trow; o is [b,t,j,512]
    size_t ob = ((size_t)(b * kT + trow) * kNJ + j) * kDIM + h * kHD;
#pragma unroll
    for (int nt = 0; nt < 4; ++nt) {
      f16x4 ov;
#pragma unroll
      for (int r = 0; r < 4; ++r) ov[r] = (f16)(oacc[nt][r] * linv);
      *(f16x4*)(o + ob + nt * 16 + fq * 4) = ov;
    }
  }
}

// ================================ launch ================================
extern "C" void kernel_launch(void* const* d_in, const int* in_sizes, int n_in,
                              void* d_out, int out_size, void* d_ws, size_t ws_size,
                              hipStream_t stream) {
  const float* x  = (const float*)d_in[0];
  const float* Wq = (const float*)d_in[1];
  const float* Wk = (const float*)d_in[2];
  const float* Wv = (const float*)d_in[3];
  const float* Wo = (const float*)d_in[4];
  const float* bo = (const float*)d_in[5];
  float* y = (float*)d_out;

  char* ws = (char*)d_ws;
  f16* xh  = (f16*)(ws);                 // 50,331,648  [j][R][d]; reused as attn out o
  f16* wT  = (f16*)(ws + 50331648);      // 37,748,736
  f16* woh = (f16*)(ws + 88080384);      //    524,288
  f16* q   = (f16*)(ws + 88604672);      // 50,331,648  blocked [b][j][h][t][d]
  f16* k   = (f16*)(ws + 138936320);     // 50,331,648  blocked [b][j][h][t][d]
  f16* v   = (f16*)(ws + 189267968);     // 50,331,648  transposed [b][j][h][d][t]
  f16* o   = xh;                         // alias: xh dead after k_qkv

  k_cvt_xj<<<4096, 256, 0, stream>>>(x, xh, (kBT * kRS) / 4);
  k_cvt<<<256, 256, 0, stream>>>(Wo, woh, (kDIM * kDIM) / 4);
  dim3 gT(256, kNJ);
  k_cvt_wT<<<gT, 256, 0, stream>>>(Wq, wT);
  k_cvt_wT<<<gT, 256, 0, stream>>>(Wk, wT + 6291456);
  k_cvt_wT<<<gT, 256, 0, stream>>>(Wv, wT + 12582912);

  k_qkv<<<dim3(64, kNJ, 3), 256, 0, stream>>>(xh, wT, q, k, v);
  k_attn<<<kBS * kNJ * kNH, 256, 0, stream>>>(q, k, v, o);
  k_outproj<<<1536, 256, 0, stream>>>(o, woh, bo, y);
}